// Round 16
// baseline (402.138 us; speedup 1.0000x reference)
//
#include <hip/hip_runtime.h>
#include <hip/hip_cooperative_groups.h>
#include <math.h>

namespace cg = cooperative_groups;

#define N_NODES 100000
#define D_EMB   64
#define KSEL    500000
#define NMENT   200000
#define ATT_H   20
#define NPAD    100352             // 784 * 128

// ws layout (float offsets)
#define WS_EB    0                 // [100000] per-node exp(beta)
#define WS_NUM   100000            // [64*64]  portrait numerator
#define WS_DEN   104096            // [64]     portrait denominator
#define WS_PORT  104160            // [64*64]  normalized portrait (fallback only)
#define WS_W     108256            // [2*64]   gate weights
#define WS_BF    108416            // bf16 row table [100000][64] bf16 (16B aligned)
#define WS_BF_BYTE ((size_t)WS_BF * 4)
#define WS_T     3308416           // bf16-pair dot table [64][NPAD] uint (16B aligned)
#define WS_TOTAL_BYTES ((size_t)(WS_T + 64 * NPAD) * 4)

#define NPB 391        // node blocks in classic kP
#define NBLK_G 784     // GEMM blocks (128 nodes x all 64 b each)
#define GRID_M 1024    // mega-kernel grid
#define GSZ    (GRID_M * 256)
#define MPB    196     // mentions per block in mega phase B (1024*196 >= 200000)
#define WPW    49      // mentions per wave

typedef __attribute__((ext_vector_type(8))) short bf16x8;
typedef __attribute__((ext_vector_type(4))) float f32x4;

__device__ __forceinline__ unsigned pack2bf(float a, float b) {
    unsigned ua = __float_as_uint(a), ub = __float_as_uint(b);
    ua = (ua + 0x7FFFu + ((ua >> 16) & 1u)) >> 16;   // RNE bf16
    ub = (ub + 0x7FFFu + ((ub >> 16) & 1u)) >> 16;
    return ua | (ub << 16);
}
__device__ __forceinline__ float uasf(unsigned u) { return __uint_as_float(u); }

// ===========================================================================
// MEGA-KERNEL: all 4 phases in one cooperative launch (saves 3x launch+drain).
// Phase A: eb + bf16 row pack + zero accum.   grid.sync()
// Phase B: mention segment-accum (49/wave, 13-deep pipeline, LDS accum).
// Phase C: gates (32 blocks) + dot-table GEMM (784 blocks).   grid.sync()
// Phase D: score 1M k's, grid-stride.
// Residency: __launch_bounds__(256,4) => <=128 VGPR => 4 blocks/CU; LDS
// 18.4KB => 4 blocks/CU; grid 1024 = 256 CU x 4 co-resident. [G16: grid sync
// only via cooperative launch]
// ===========================================================================
__global__ __launch_bounds__(256, 4) void kMega(
        const float* __restrict__ ge, const float* __restrict__ utter,
        const int* __restrict__ mi, const int* __restrict__ mbi,
        const int* __restrict__ sel, const int* __restrict__ selb,
        const int* __restrict__ selg, const int* __restrict__ grpb,
        const int* __restrict__ lastI, const int* __restrict__ intentI,
        const float* __restrict__ masks,
        const float* __restrict__ attW, const float* __restrict__ attV,
        const float* __restrict__ W1w, const float* __restrict__ W1b,
        const float* __restrict__ W2w, const float* __restrict__ W2b,
        const float* __restrict__ intentEmb,
        float* __restrict__ ws, float* __restrict__ out) {
    cg::grid_group grid = cg::this_grid();
    __shared__ float smem[4608];           // union: lacc+lden | sQ | sWd
    int tid = threadIdx.x, bid = blockIdx.x;
    int gtid = bid * 256 + tid;

    // ---------------- Phase A: eb + pack + zero ----------------
    if (gtid < 64 * 64 + 64) ws[WS_NUM + gtid] = 0.f;
    if (gtid < N_NODES) {
        const float4* g4 = (const float4*)(ge + (size_t)gtid * D_EMB);
        float4 x[16];
#pragma unroll
        for (int i = 0; i < 16; ++i) x[i] = g4[i];

        uint4* dst = (uint4*)((char*)ws + WS_BF_BYTE + (size_t)gtid * 128);
#pragma unroll
        for (int j = 0; j < 8; ++j) {
            uint4 o;
            o.x = pack2bf(x[2*j].x,   x[2*j].y);
            o.y = pack2bf(x[2*j].z,   x[2*j].w);
            o.z = pack2bf(x[2*j+1].x, x[2*j+1].y);
            o.w = pack2bf(x[2*j+1].z, x[2*j+1].w);
            dst[j] = o;
        }

        float beta = 0.f;
#pragma unroll
        for (int j = 0; j < ATT_H; ++j) {
            float h = 0.f;
#pragma unroll
            for (int i = 0; i < 16; ++i) {
                float4 w = ((const float4*)(attW + j * D_EMB))[i];
                h += w.x * x[i].x + w.y * x[i].y + w.z * x[i].z + w.w * x[i].w;
            }
            beta += attV[j] * tanhf(h);
        }
        ws[WS_EB + gtid] = expf(beta);
    }
    grid.sync();

    // ---------------- Phase B: mention segment accumulation ----------------
    {
        float* lacc = smem;                 // [64*64]
        float* lden = smem + 4096;          // [64]
        for (int i = tid; i < 4160; i += 256) smem[i] = 0.f;
        __syncthreads();

        const unsigned short* bft = (const unsigned short*)((const char*)ws + WS_BF_BYTE);
        int lane = tid & 63;
        int grp  = lane >> 4, lp = lane & 15;
        int wid  = tid >> 6;
        int mStart = bid * MPB;
        int mEnd   = min(mStart + MPB, NMENT);
        int s0     = mStart + wid * WPW;
        int sEnd   = min(s0 + WPW, mEnd);

        if (s0 < mEnd) {
            int len = sEnd - s0;
            bool v  = lane < len;
            int lastB = mbi[sEnd - 1];
            int nd  = v ? mi[s0 + lane]  : 0;
            int bb  = v ? mbi[s0 + lane] : lastB;
            float ebv = v ? ws[WS_EB + nd] : 0.f;
            int code  = nd | (bb << 17);

            int cd[13]; float e13[13]; uint2 rr[13];
#pragma unroll
            for (int i = 0; i < 13; ++i) {
                int u = 4 * i + grp;
                cd[i]  = __shfl(code, u);
                e13[i] = __shfl(ebv, u);
            }
#pragma unroll
            for (int i = 0; i < 13; ++i)
                rr[i] = *(const uint2*)(bft + (size_t)(cd[i] & 0x1FFFF) * 64 + lp * 4);

            int curb = (__shfl(code, 0) >> 17) & 63;
            float4 acc = make_float4(0.f, 0.f, 0.f, 0.f);
            float dacc = 0.f;
#pragma unroll
            for (int i = 0; i < 13; ++i) {
                int u = 4 * i + grp;
                int b = (cd[i] >> 17) & 63;
                if (u < len && b != curb) {        // group-uniform, rare
                    atomicAdd(&lacc[curb * 64 + lp * 4 + 0], acc.x);
                    atomicAdd(&lacc[curb * 64 + lp * 4 + 1], acc.y);
                    atomicAdd(&lacc[curb * 64 + lp * 4 + 2], acc.z);
                    atomicAdd(&lacc[curb * 64 + lp * 4 + 3], acc.w);
                    if (lp == 0) atomicAdd(&lden[curb], dacc);
                    acc = make_float4(0.f, 0.f, 0.f, 0.f); dacc = 0.f; curb = b;
                }
                float e = e13[i];
                acc.x = fmaf(e, uasf(rr[i].x << 16),         acc.x);
                acc.y = fmaf(e, uasf(rr[i].x & 0xFFFF0000u), acc.y);
                acc.z = fmaf(e, uasf(rr[i].y << 16),         acc.z);
                acc.w = fmaf(e, uasf(rr[i].y & 0xFFFF0000u), acc.w);
                dacc += e;
            }
            atomicAdd(&lacc[curb * 64 + lp * 4 + 0], acc.x);
            atomicAdd(&lacc[curb * 64 + lp * 4 + 1], acc.y);
            atomicAdd(&lacc[curb * 64 + lp * 4 + 2], acc.z);
            atomicAdd(&lacc[curb * 64 + lp * 4 + 3], acc.w);
            if (lp == 0) atomicAdd(&lden[curb], dacc);
        }
        __syncthreads();

        if (mStart < mEnd) {
            int b0 = mbi[mStart], b1 = mbi[mEnd - 1];
            int nb = b1 - b0 + 1;
            for (int idx = tid; idx < nb * 64; idx += 256) {
                int b2 = b0 + (idx >> 6), d = idx & 63;
                float v = lacc[b2 * 64 + d];
                if (v != 0.f) atomicAdd(&ws[WS_NUM + b2 * 64 + d], v);
            }
            if (tid < nb) {
                float v = lden[b0 + tid];
                if (v != 0.f) atomicAdd(&ws[WS_DEN + b0 + tid], v);
            }
        }
    }
    grid.sync();

    // ---------------- Phase C: gates (blocks 784..815) + GEMM (0..783) -----
    if (bid >= NBLK_G && bid < NBLK_G + 32) {
        int bi = (bid - NBLK_G) * 4 + (tid >> 6);
        int d  = tid & 63;
        int l  = bi >> 6;
        int gb = grpb[bi];
        float pd = ws[WS_NUM + gb * 64 + d] / ws[WS_DEN + gb];
        int last = lastI[bi];
        float gl = (last < N_NODES) ? ge[(size_t)last * 64 + d] : 0.f;
        float ie = intentEmb[intentI[bi] * 64 + d];
        const float* Ww = l ? W2w : W1w;
        float bias      = l ? W2b[0] : W1b[0];
        float val = utter[gb * 64 + d] * Ww[d]
                  + pd * Ww[64 + d]
                  + gl * Ww[128 + d]
                  + ie * Ww[192 + d];
#pragma unroll
        for (int off = 32; off; off >>= 1) val += __shfl_xor(val, off);
        if (d == 0) ws[WS_W + bi] = 1.f / (1.f + expf(-(val + bias)));
    } else if (bid < NBLK_G) {
        unsigned* sQ = (unsigned*)smem;     // [128*36]
        for (int i = tid; i < 128 * 32; i += 256) {
            int r = i >> 5, c32 = i & 31;
            int k2 = c32 * 2;
            float a, b;
            if (r < 64) {
                a = utter[r * 64 + k2]; b = utter[r * 64 + k2 + 1];
            } else {
                int q = r - 64;
                float dn = ws[WS_DEN + q];
                a = ws[WS_NUM + q * 64 + k2] / dn;
                b = ws[WS_NUM + q * 64 + k2 + 1] / dn;
            }
            sQ[r * 36 + c32] = pack2bf(a, b);
        }
        __syncthreads();

        int l = tid & 63, w = tid >> 6;
        int r16 = l & 15, kb = l >> 4;
        int nb0 = bid * 128 + w * 32;

        float4 ar[2][2][2];
#pragma unroll
        for (int t = 0; t < 2; ++t) {
            int node = nb0 + t * 16 + r16;
            const float* p = ge + (size_t)node * 64 + kb * 8;
#pragma unroll
            for (int s = 0; s < 2; ++s) {
                float4 z = make_float4(0.f, 0.f, 0.f, 0.f);
                ar[t][s][0] = (node < N_NODES) ? *(const float4*)(p + s * 32)     : z;
                ar[t][s][1] = (node < N_NODES) ? *(const float4*)(p + s * 32 + 4) : z;
            }
        }
        bf16x8 Af[2][2];
#pragma unroll
        for (int t = 0; t < 2; ++t)
#pragma unroll
            for (int s = 0; s < 2; ++s) {
                uint4 u = make_uint4(pack2bf(ar[t][s][0].x, ar[t][s][0].y),
                                     pack2bf(ar[t][s][0].z, ar[t][s][0].w),
                                     pack2bf(ar[t][s][1].x, ar[t][s][1].y),
                                     pack2bf(ar[t][s][1].z, ar[t][s][1].w));
                Af[t][s] = __builtin_bit_cast(bf16x8, u);
            }

        unsigned* Tu = (unsigned*)(ws + WS_T);
#pragma unroll 1
        for (int qq = 0; qq < 4; ++qq) {
            bf16x8 Bf[2][2];
#pragma unroll
            for (int s = 0; s < 2; ++s) {
                uint4 u0 = *(const uint4*)&sQ[(qq * 16 + r16) * 36 + s * 16 + kb * 4];
                uint4 u1 = *(const uint4*)&sQ[(64 + qq * 16 + r16) * 36 + s * 16 + kb * 4];
                Bf[0][s] = __builtin_bit_cast(bf16x8, u0);
                Bf[1][s] = __builtin_bit_cast(bf16x8, u1);
            }
            f32x4 acc[2][2];
#pragma unroll
            for (int t = 0; t < 2; ++t)
#pragma unroll
                for (int c = 0; c < 2; ++c) acc[t][c] = (f32x4){0.f, 0.f, 0.f, 0.f};
#pragma unroll
            for (int t = 0; t < 2; ++t)
#pragma unroll
                for (int s = 0; s < 2; ++s)
#pragma unroll
                    for (int c = 0; c < 2; ++c)
                        acc[t][c] = __builtin_amdgcn_mfma_f32_16x16x32_bf16(Af[t][s], Bf[c][s], acc[t][c], 0, 0, 0);

            int b = qq * 16 + r16;
#pragma unroll
            for (int t = 0; t < 2; ++t) {
                uint4 o;
                o.x = pack2bf(acc[t][0][0], acc[t][1][0]);
                o.y = pack2bf(acc[t][0][1], acc[t][1][1]);
                o.z = pack2bf(acc[t][0][2], acc[t][1][2]);
                o.w = pack2bf(acc[t][0][3], acc[t][1][3]);
                *(uint4*)(Tu + (size_t)b * NPAD + nb0 + t * 16 + kb * 4) = o;
            }
        }
    }
    grid.sync();

    // ---------------- Phase D: score 1M k's ----------------
    if (tid < 128) smem[tid] = ws[WS_W + tid];
    __syncthreads();
    const unsigned* Tu = (const unsigned*)(ws + WS_T);
    for (int kk = gtid; kk < 2 * KSEL; kk += GSZ) {
        int n = sel[kk], b = selb[kk], g = selg[kk];
        unsigned t = Tu[(size_t)b * NPAD + n];
        float du = uasf(t << 16), dp = uasf(t & 0xFFFF0000u);
        float cu, cp;
        if (kk < KSEL) {
            float wv = smem[g]; cu = wv; cp = 1.f - wv;
        } else {
            float mk = masks[kk];
            float lw = smem[b], w1 = smem[64 + g];
            cu = fmaf(mk, w1, lw);
            cp = fmaf(mk, 1.f - w1, 1.f - lw);
        }
        out[kk] = cu * du + cp * dp;
    }
}

// ===========================================================================
// Classic fallback path (round-15 proven, 93.7us) — used if cooperative
// launch fails (capture or residency) or ws too small.
// ===========================================================================
template<bool PACK>
__global__ __launch_bounds__(256) void kP(const float* __restrict__ ge,
                                          const float* __restrict__ attW,
                                          const float* __restrict__ attV,
                                          float* __restrict__ ws) {
    int tid = blockIdx.x * 256 + threadIdx.x;
    if (tid < 64 * 64 + 64) ws[WS_NUM + tid] = 0.f;
    if (tid >= N_NODES) return;
    const float4* g4 = (const float4*)(ge + (size_t)tid * D_EMB);
    float4 x[16];
#pragma unroll
    for (int i = 0; i < 16; ++i) x[i] = g4[i];
    if constexpr (PACK) {
        uint4* dst = (uint4*)((char*)ws + WS_BF_BYTE + (size_t)tid * 128);
#pragma unroll
        for (int j = 0; j < 8; ++j) {
            uint4 o;
            o.x = pack2bf(x[2*j].x,   x[2*j].y);
            o.y = pack2bf(x[2*j].z,   x[2*j].w);
            o.z = pack2bf(x[2*j+1].x, x[2*j+1].y);
            o.w = pack2bf(x[2*j+1].z, x[2*j+1].w);
            dst[j] = o;
        }
    }
    float beta = 0.f;
#pragma unroll
    for (int j = 0; j < ATT_H; ++j) {
        float h = 0.f;
#pragma unroll
        for (int i = 0; i < 16; ++i) {
            float4 w = ((const float4*)(attW + j * D_EMB))[i];
            h += w.x * x[i].x + w.y * x[i].y + w.z * x[i].z + w.w * x[i].w;
        }
        beta += attV[j] * tanhf(h);
    }
    ws[WS_EB + tid] = expf(beta);
}

__global__ __launch_bounds__(256, 8) void kA2n(const int* __restrict__ mi,
                                               const int* __restrict__ mbi,
                                               float* __restrict__ ws) {
    __shared__ float lacc[64 * 64];
    __shared__ float lden[64];
    for (int i = threadIdx.x; i < 64 * 64; i += 256) lacc[i] = 0.f;
    if (threadIdx.x < 64) lden[threadIdx.x] = 0.f;
    __syncthreads();
    const unsigned short* bft = (const unsigned short*)((const char*)ws + WS_BF_BYTE);
    int lane = threadIdx.x & 63;
    int grp  = lane >> 4, lp = lane & 15;
    int wave = blockIdx.x * 4 + (threadIdx.x >> 6);
    int s = wave * 25;
    bool valid = lane < 25;
    int lastB  = mbi[s + 24];
    int nd     = valid ? mi[s + lane] : 0;
    int bb     = valid ? mbi[s + lane] : lastB;
    float ebv  = valid ? ws[WS_EB + nd] : 0.f;
    int code   = nd | (bb << 17);
    int cd[7]; float e7[7]; uint2 rr[7];
#pragma unroll
    for (int i = 0; i < 7; ++i) {
        int u = 4 * i + grp;
        cd[i] = __shfl(code, u);
        e7[i] = __shfl(ebv, u);
    }
#pragma unroll
    for (int i = 0; i < 7; ++i)
        rr[i] = *(const uint2*)(bft + (size_t)(cd[i] & 0x1FFFF) * 64 + lp * 4);
    int curb = (__shfl(code, 0) >> 17) & 63;
    float4 acc = make_float4(0.f, 0.f, 0.f, 0.f);
    float dacc = 0.f;
#pragma unroll
    for (int i = 0; i < 7; ++i) {
        int u = 4 * i + grp;
        int b = (cd[i] >> 17) & 63;
        if (u < 25 && b != curb) {
            atomicAdd(&lacc[curb * 64 + lp * 4 + 0], acc.x);
            atomicAdd(&lacc[curb * 64 + lp * 4 + 1], acc.y);
            atomicAdd(&lacc[curb * 64 + lp * 4 + 2], acc.z);
            atomicAdd(&lacc[curb * 64 + lp * 4 + 3], acc.w);
            if (lp == 0) atomicAdd(&lden[curb], dacc);
            acc = make_float4(0.f, 0.f, 0.f, 0.f); dacc = 0.f; curb = b;
        }
        float e = e7[i];
        acc.x = fmaf(e, uasf(rr[i].x << 16),         acc.x);
        acc.y = fmaf(e, uasf(rr[i].x & 0xFFFF0000u), acc.y);
        acc.z = fmaf(e, uasf(rr[i].y << 16),         acc.z);
        acc.w = fmaf(e, uasf(rr[i].y & 0xFFFF0000u), acc.w);
        dacc += e;
    }
    atomicAdd(&lacc[curb * 64 + lp * 4 + 0], acc.x);
    atomicAdd(&lacc[curb * 64 + lp * 4 + 1], acc.y);
    atomicAdd(&lacc[curb * 64 + lp * 4 + 2], acc.z);
    atomicAdd(&lacc[curb * 64 + lp * 4 + 3], acc.w);
    if (lp == 0) atomicAdd(&lden[curb], dacc);
    __syncthreads();
    int sB = blockIdx.x * 100;
    int b0 = mbi[sB];
    int b1 = mbi[sB + 99];
    int nb = b1 - b0 + 1;
    for (int idx = threadIdx.x; idx < nb * 64; idx += 256) {
        int b2 = b0 + (idx >> 6), d = idx & 63;
        float v = lacc[b2 * 64 + d];
        if (v != 0.f) atomicAdd(&ws[WS_NUM + b2 * 64 + d], v);
    }
    if (threadIdx.x < nb) {
        float v = lden[b0 + threadIdx.x];
        if (v != 0.f) atomicAdd(&ws[WS_DEN + b0 + threadIdx.x], v);
    }
}

__global__ __launch_bounds__(256) void kG(const float* __restrict__ ge,
                                          const float* __restrict__ utter,
                                          const int* __restrict__ grpb,
                                          const int* __restrict__ lastI,
                                          const int* __restrict__ intentI,
                                          const float* __restrict__ W1w,
                                          const float* __restrict__ W1b,
                                          const float* __restrict__ W2w,
                                          const float* __restrict__ W2b,
                                          const float* __restrict__ intentEmb,
                                          float* __restrict__ ws) {
    int bid = blockIdx.x;
    if (bid >= NBLK_G) {
        int bi = (bid - NBLK_G) * 4 + (threadIdx.x >> 6);
        int d  = threadIdx.x & 63;
        int l  = bi >> 6;
        int gb = grpb[bi];
        float pd = ws[WS_NUM + gb * 64 + d] / ws[WS_DEN + gb];
        int last = lastI[bi];
        float gl = (last < N_NODES) ? ge[(size_t)last * 64 + d] : 0.f;
        float ie = intentEmb[intentI[bi] * 64 + d];
        const float* Ww = l ? W2w : W1w;
        float bias      = l ? W2b[0] : W1b[0];
        float val = utter[gb * 64 + d] * Ww[d]
                  + pd * Ww[64 + d]
                  + gl * Ww[128 + d]
                  + ie * Ww[192 + d];
#pragma unroll
        for (int off = 32; off; off >>= 1) val += __shfl_xor(val, off);
        if (d == 0) ws[WS_W + bi] = 1.f / (1.f + expf(-(val + bias)));
        return;
    }
    __shared__ unsigned sQ[128 * 36];
    int tid = threadIdx.x;
    for (int i = tid; i < 128 * 32; i += 256) {
        int r = i >> 5, c32 = i & 31;
        int k2 = c32 * 2;
        float a, b;
        if (r < 64) {
            a = utter[r * 64 + k2]; b = utter[r * 64 + k2 + 1];
        } else {
            int q = r - 64;
            float dn = ws[WS_DEN + q];
            a = ws[WS_NUM + q * 64 + k2] / dn;
            b = ws[WS_NUM + q * 64 + k2 + 1] / dn;
        }
        sQ[r * 36 + c32] = pack2bf(a, b);
    }
    __syncthreads();
    int l = tid & 63, w = tid >> 6;
    int r16 = l & 15, kb = l >> 4;
    int nb0 = bid * 128 + w * 32;
    float4 ar[2][2][2];
#pragma unroll
    for (int t = 0; t < 2; ++t) {
        int node = nb0 + t * 16 + r16;
        const float* p = ge + (size_t)node * 64 + kb * 8;
#pragma unroll
        for (int s = 0; s < 2; ++s) {
            float4 z = make_float4(0.f, 0.f, 0.f, 0.f);
            ar[t][s][0] = (node < N_NODES) ? *(const float4*)(p + s * 32)     : z;
            ar[t][s][1] = (node < N_NODES) ? *(const float4*)(p + s * 32 + 4) : z;
        }
    }
    bf16x8 Af[2][2];
#pragma unroll
    for (int t = 0; t < 2; ++t)
#pragma unroll
        for (int s = 0; s < 2; ++s) {
            uint4 u = make_uint4(pack2bf(ar[t][s][0].x, ar[t][s][0].y),
                                 pack2bf(ar[t][s][0].z, ar[t][s][0].w),
                                 pack2bf(ar[t][s][1].x, ar[t][s][1].y),
                                 pack2bf(ar[t][s][1].z, ar[t][s][1].w));
            Af[t][s] = __builtin_bit_cast(bf16x8, u);
        }
    unsigned* Tu = (unsigned*)(ws + WS_T);
#pragma unroll 1
    for (int qq = 0; qq < 4; ++qq) {
        bf16x8 Bf[2][2];
#pragma unroll
        for (int s = 0; s < 2; ++s) {
            uint4 u0 = *(const uint4*)&sQ[(qq * 16 + r16) * 36 + s * 16 + kb * 4];
            uint4 u1 = *(const uint4*)&sQ[(64 + qq * 16 + r16) * 36 + s * 16 + kb * 4];
            Bf[0][s] = __builtin_bit_cast(bf16x8, u0);
            Bf[1][s] = __builtin_bit_cast(bf16x8, u1);
        }
        f32x4 acc[2][2];
#pragma unroll
        for (int t = 0; t < 2; ++t)
#pragma unroll
            for (int c = 0; c < 2; ++c) acc[t][c] = (f32x4){0.f, 0.f, 0.f, 0.f};
#pragma unroll
        for (int t = 0; t < 2; ++t)
#pragma unroll
            for (int s = 0; s < 2; ++s)
#pragma unroll
                for (int c = 0; c < 2; ++c)
                    acc[t][c] = __builtin_amdgcn_mfma_f32_16x16x32_bf16(Af[t][s], Bf[c][s], acc[t][c], 0, 0, 0);
        int b = qq * 16 + r16;
#pragma unroll
        for (int t = 0; t < 2; ++t) {
            uint4 o;
            o.x = pack2bf(acc[t][0][0], acc[t][1][0]);
            o.y = pack2bf(acc[t][0][1], acc[t][1][1]);
            o.z = pack2bf(acc[t][0][2], acc[t][1][2]);
            o.w = pack2bf(acc[t][0][3], acc[t][1][3]);
            *(uint4*)(Tu + (size_t)b * NPAD + nb0 + t * 16 + kb * 4) = o;
        }
    }
}

__global__ __launch_bounds__(256) void kS(const int* __restrict__ sel,
                                          const int* __restrict__ selb,
                                          const int* __restrict__ selg,
                                          const float* __restrict__ masks,
                                          const float* __restrict__ ws,
                                          float* __restrict__ out) {
    __shared__ float sWd[128];
    if (threadIdx.x < 128) sWd[threadIdx.x] = ws[WS_W + threadIdx.x];
    __syncthreads();
    int kk = blockIdx.x * 256 + threadIdx.x;
    if (kk >= 2 * KSEL) return;
    int n = sel[kk], b = selb[kk], g = selg[kk];
    const unsigned* Tu = (const unsigned*)(ws + WS_T);
    unsigned t = Tu[(size_t)b * NPAD + n];
    float du = uasf(t << 16), dp = uasf(t & 0xFFFF0000u);
    float cu, cp;
    if (kk < KSEL) {
        float wv = sWd[g]; cu = wv; cp = 1.f - wv;
    } else {
        float mk = masks[kk];
        float lw = sWd[b], w1 = sWd[64 + g];
        cu = fmaf(mk, w1, lw);
        cp = fmaf(mk, 1.f - w1, 1.f - lw);
    }
    out[kk] = cu * du + cp * dp;
}

extern "C" void kernel_launch(void* const* d_in, const int* in_sizes, int n_in,
                              void* d_out, int out_size, void* d_ws, size_t ws_size,
                              hipStream_t stream) {
    const float* ge        = (const float*)d_in[0];
    const float* utter     = (const float*)d_in[1];
    const int*   mi        = (const int*)d_in[2];
    const int*   mbi       = (const int*)d_in[3];
    const int*   sel       = (const int*)d_in[4];
    const int*   selb      = (const int*)d_in[5];
    const int*   selg      = (const int*)d_in[6];
    const int*   grpb      = (const int*)d_in[7];
    const int*   lastI     = (const int*)d_in[8];
    const int*   intentI   = (const int*)d_in[9];
    const float* masks     = (const float*)d_in[10];
    const float* attW      = (const float*)d_in[11];
    const float* attV      = (const float*)d_in[12];
    const float* W1w       = (const float*)d_in[13];
    const float* W1b       = (const float*)d_in[14];
    const float* W2w       = (const float*)d_in[15];
    const float* W2b       = (const float*)d_in[16];
    const float* intentEmb = (const float*)d_in[17];
    float* ws  = (float*)d_ws;
    float* out = (float*)d_out;

    bool full = ws_size >= WS_TOTAL_BYTES;
    bool done = false;

    if (full) {
        void* args[] = {(void*)&ge, (void*)&utter, (void*)&mi, (void*)&mbi,
                        (void*)&sel, (void*)&selb, (void*)&selg, (void*)&grpb,
                        (void*)&lastI, (void*)&intentI, (void*)&masks,
                        (void*)&attW, (void*)&attV, (void*)&W1w, (void*)&W1b,
                        (void*)&W2w, (void*)&W2b, (void*)&intentEmb,
                        (void*)&ws, (void*)&out};
        hipError_t e = hipLaunchCooperativeKernel((const void*)kMega,
                                                  dim3(GRID_M), dim3(256),
                                                  args, 0, stream);
        done = (e == hipSuccess);
    }

    if (!done && full) {
        kP<true><<<dim3(NPB), dim3(256), 0, stream>>>(ge, attW, attV, ws);
        kA2n<<<dim3(2000), dim3(256), 0, stream>>>(mi, mbi, ws);
        kG<<<dim3(NBLK_G + 32), dim3(256), 0, stream>>>(
            ge, utter, grpb, lastI, intentI, W1w, W1b, W2w, W2b, intentEmb, ws);
        kS<<<dim3((2 * KSEL + 255) / 256), dim3(256), 0, stream>>>(sel, selb, selg,
                                                                   masks, ws, out);
    }
}

// Round 17
// 81.289 us; speedup vs baseline: 4.9470x; 4.9470x over previous
//
#include <hip/hip_runtime.h>
#include <math.h>

#define N_NODES 100000
#define D_EMB   64
#define KSEL    500000
#define NMENT   200000
#define ATT_H   20

// ws layout (float offsets) — identical to round 8 (best measured: 79.9us)
#define WS_EB    0                 // [100000] per-node exp(beta)
#define WS_NUM   100000            // [64*64]  portrait numerator
#define WS_DEN   104096            // [64]     portrait denominator
#define WS_PORT  104160            // [64*64]  normalized portrait
#define WS_W     108256            // [2*64]   gate weights
#define WS_KCODE 108384            // [1000000] int: sel | b<<17 | g<<23
#define WS_MCODE 1108384           // [200000]  (reserved, unused)
#define WS_BF_FLOAT_OFF 1308416    // bf16 row table (12.8MB, 16B aligned)
#define WS_BF_BYTE ((size_t)WS_BF_FLOAT_OFF * 4)
#define WS_TOTAL_BYTES ((size_t)(WS_BF_FLOAT_OFF + N_NODES * 32) * 4)

#define NPB 391    // node blocks in kP
#define KCB 977    // kcode packer blocks

typedef __attribute__((ext_vector_type(8))) short bf16x8;

__device__ __forceinline__ unsigned pack2bf(float a, float b) {
    unsigned ua = __float_as_uint(a), ub = __float_as_uint(b);
    ua = (ua + 0x7FFFu + ((ua >> 16) & 1u)) >> 16;   // RNE bf16
    ub = (ub + 0x7FFFu + ((ub >> 16) & 1u)) >> 16;
    return ua | (ub << 16);
}
__device__ __forceinline__ float uasf(unsigned u) { return __uint_as_float(u); }

// ---------------------------------------------------------------------------
// Kernel P (fused): blocks [0,NPB): per-node eb + bf16 row pack + accum zero.
// blocks [NPB, NPB+KCB): pack kcode (sel|b<<17|g<<23).
// ---------------------------------------------------------------------------
template<bool PACK>
__global__ __launch_bounds__(256) void kP(const float* __restrict__ ge,
                                          const float* __restrict__ attW,
                                          const float* __restrict__ attV,
                                          const int* __restrict__ sel,
                                          const int* __restrict__ selb,
                                          const int* __restrict__ selg,
                                          float* __restrict__ ws) {
    int bid = blockIdx.x;
    if (PACK && bid >= NPB) {
        int base = (bid - NPB) * 1024 + threadIdx.x * 4;
        int* kc = (int*)ws + WS_KCODE;
        if (base + 3 < 2 * KSEL) {
            int4 a = *(const int4*)(sel + base);
            int4 b = *(const int4*)(selb + base);
            int4 g = *(const int4*)(selg + base);
            int4 o;
            o.x = a.x | (b.x << 17) | (g.x << 23);
            o.y = a.y | (b.y << 17) | (g.y << 23);
            o.z = a.z | (b.z << 17) | (g.z << 23);
            o.w = a.w | (b.w << 17) | (g.w << 23);
            *(int4*)(kc + base) = o;
        } else {
            for (int i = base; i < 2 * KSEL; ++i)
                kc[i] = sel[i] | (selb[i] << 17) | (selg[i] << 23);
        }
        return;
    }

    int tid = bid * 256 + threadIdx.x;
    if (tid < 64 * 64 + 64) ws[WS_NUM + tid] = 0.f;   // zero num + den
    if (tid >= N_NODES) return;

    const float4* g4 = (const float4*)(ge + (size_t)tid * D_EMB);
    float4 x[16];
#pragma unroll
    for (int i = 0; i < 16; ++i) x[i] = g4[i];

    if constexpr (PACK) {
        uint4* dst = (uint4*)((char*)ws + WS_BF_BYTE + (size_t)tid * 128);
#pragma unroll
        for (int j = 0; j < 8; ++j) {
            uint4 o;
            o.x = pack2bf(x[2*j].x,   x[2*j].y);
            o.y = pack2bf(x[2*j].z,   x[2*j].w);
            o.z = pack2bf(x[2*j+1].x, x[2*j+1].y);
            o.w = pack2bf(x[2*j+1].z, x[2*j+1].w);
            dst[j] = o;
        }
    }

    float beta = 0.f;
#pragma unroll
    for (int j = 0; j < ATT_H; ++j) {
        float h = 0.f;
#pragma unroll
        for (int i = 0; i < 16; ++i) {
            float4 w = ((const float4*)(attW + j * D_EMB))[i];
            h += w.x * x[i].x + w.y * x[i].y + w.z * x[i].z + w.w * x[i].w;
        }
        beta += attV[j] * tanhf(h);
    }
    ws[WS_EB + tid] = expf(beta);
}

// ---------------------------------------------------------------------------
// Kernel A2 (round-14/15 proven): 2000 blocks x 4 waves; 25 mentions/wave.
// Direct mi/mbi strip preload -> __shfl broadcast; 7 bf16 rows in flight;
// register accumulate; rare flush to LDS; one small global flush per block.
// ---------------------------------------------------------------------------
__global__ __launch_bounds__(256, 8) void kA2n(const int* __restrict__ mi,
                                               const int* __restrict__ mbi,
                                               float* __restrict__ ws) {
    __shared__ float lacc[64 * 64];
    __shared__ float lden[64];
    for (int i = threadIdx.x; i < 64 * 64; i += 256) lacc[i] = 0.f;
    if (threadIdx.x < 64) lden[threadIdx.x] = 0.f;
    __syncthreads();

    const unsigned short* bft = (const unsigned short*)((const char*)ws + WS_BF_BYTE);

    int lane = threadIdx.x & 63;
    int grp  = lane >> 4, lp = lane & 15;
    int wave = blockIdx.x * 4 + (threadIdx.x >> 6);
    int s = wave * 25;                       // 8000 waves x 25 = 200000 exactly

    bool valid = lane < 25;
    int lastB  = mbi[s + 24];
    int nd     = valid ? mi[s + lane] : 0;
    int bb     = valid ? mbi[s + lane] : lastB;
    float ebv  = valid ? ws[WS_EB + nd] : 0.f;
    int code   = nd | (bb << 17);            // nd < 2^17, bb < 64

    int cd[7]; float e7[7]; uint2 rr[7];
#pragma unroll
    for (int i = 0; i < 7; ++i) {
        int u = 4 * i + grp;                 // 0..27 (25..27 -> eb=0 lanes)
        cd[i] = __shfl(code, u);
        e7[i] = __shfl(ebv, u);
    }
#pragma unroll
    for (int i = 0; i < 7; ++i)
        rr[i] = *(const uint2*)(bft + (size_t)(cd[i] & 0x1FFFF) * 64 + lp * 4);

    int curb = (__shfl(code, 0) >> 17) & 63;
    float4 acc = make_float4(0.f, 0.f, 0.f, 0.f);
    float dacc = 0.f;
#pragma unroll
    for (int i = 0; i < 7; ++i) {
        int u = 4 * i + grp;
        int b = (cd[i] >> 17) & 63;
        if (u < 25 && b != curb) {           // group-uniform, rare
            atomicAdd(&lacc[curb * 64 + lp * 4 + 0], acc.x);
            atomicAdd(&lacc[curb * 64 + lp * 4 + 1], acc.y);
            atomicAdd(&lacc[curb * 64 + lp * 4 + 2], acc.z);
            atomicAdd(&lacc[curb * 64 + lp * 4 + 3], acc.w);
            if (lp == 0) atomicAdd(&lden[curb], dacc);
            acc = make_float4(0.f, 0.f, 0.f, 0.f); dacc = 0.f; curb = b;
        }
        float e = e7[i];
        acc.x = fmaf(e, uasf(rr[i].x << 16),         acc.x);
        acc.y = fmaf(e, uasf(rr[i].x & 0xFFFF0000u), acc.y);
        acc.z = fmaf(e, uasf(rr[i].y << 16),         acc.z);
        acc.w = fmaf(e, uasf(rr[i].y & 0xFFFF0000u), acc.w);
        dacc += e;
    }
    atomicAdd(&lacc[curb * 64 + lp * 4 + 0], acc.x);
    atomicAdd(&lacc[curb * 64 + lp * 4 + 1], acc.y);
    atomicAdd(&lacc[curb * 64 + lp * 4 + 2], acc.z);
    atomicAdd(&lacc[curb * 64 + lp * 4 + 3], acc.w);
    if (lp == 0) atomicAdd(&lden[curb], dacc);
    __syncthreads();

    // block flush: strip covers batches [b0, b1] (sorted mbi)
    int sB = blockIdx.x * 100;               // 2000 blocks x 100 = 200000
    int b0 = mbi[sB];
    int b1 = mbi[sB + 99];
    int nb = b1 - b0 + 1;
    for (int idx = threadIdx.x; idx < nb * 64; idx += 256) {
        int b2 = b0 + (idx >> 6), d = idx & 63;
        float v = lacc[b2 * 64 + d];
        if (v != 0.f) atomicAdd(&ws[WS_NUM + b2 * 64 + d], v);
    }
    if (threadIdx.x < nb) {
        float v = lden[b0 + threadIdx.x];
        if (v != 0.f) atomicAdd(&ws[WS_DEN + b0 + threadIdx.x], v);
    }
}

// ---------------------------------------------------------------------------
// Kernel BW: normalize portrait + compute layer gate weights (128 blocks).
// ---------------------------------------------------------------------------
__global__ __launch_bounds__(64) void kBW(const float* __restrict__ ge,
                                          const float* __restrict__ utter,
                                          const int* __restrict__ grpb,
                                          const int* __restrict__ lastI,
                                          const int* __restrict__ intentI,
                                          const float* __restrict__ W1w,
                                          const float* __restrict__ W1b,
                                          const float* __restrict__ W2w,
                                          const float* __restrict__ W2b,
                                          const float* __restrict__ intentEmb,
                                          float* __restrict__ ws) {
    int bi = blockIdx.x;
    int l  = bi >> 6;
    int g  = bi & 63;
    int d  = threadIdx.x;

    if (l == 0) {
        ws[WS_PORT + g * 64 + d] = ws[WS_NUM + g * 64 + d] / ws[WS_DEN + g];
    }
    int gb = grpb[bi];
    float pd = ws[WS_NUM + gb * 64 + d] / ws[WS_DEN + gb];

    int last = lastI[bi];
    float gl = (last < N_NODES) ? ge[(size_t)last * D_EMB + d] : 0.f;
    int it = intentI[bi];
    float ie = intentEmb[it * D_EMB + d];

    const float* Ww = (l == 0) ? W1w : W2w;
    float bias      = (l == 0) ? W1b[0] : W2b[0];

    float val = utter[gb * D_EMB + d] * Ww[d]
              + pd * Ww[64 + d]
              + gl * Ww[128 + d]
              + ie * Ww[192 + d];
#pragma unroll
    for (int off = 32; off; off >>= 1) val += __shfl_xor(val, off);
    if (d == 0) ws[WS_W + bi] = 1.f / (1.f + expf(-(val + bias)));
}

// ---------------------------------------------------------------------------
// Kernel C (round-8 proven): 8 lanes per k (8 k's per wave-iteration), bf16
// rows as uint4 (16B/lane), packed codes (1 load/k), masks only for layer-2.
// 4-slot rotation: 2 codes + 2 rows in flight per wave.
// ---------------------------------------------------------------------------
__global__ __launch_bounds__(512, 8) void kCn(const float* __restrict__ utter,
                                              const float* __restrict__ masks,
                                              const float* __restrict__ ws,
                                              float* __restrict__ out) {
    __shared__ float4 sU[64 * 17];
    __shared__ float4 sP[64 * 17];
    __shared__ float  sWd[128];

    for (int i = threadIdx.x; i < 64 * 16; i += 512) {
        int r = i >> 4, c = i & 15;
        sU[r * 17 + c] = ((const float4*)utter)[i];
        sP[r * 17 + c] = ((const float4*)(ws + WS_PORT))[i];
    }
    if (threadIdx.x < 128) sWd[threadIdx.x] = ws[WS_W + threadIdx.x];
    __syncthreads();

    int lane = threadIdx.x & 63;
    int wave = blockIdx.x * 8 + (threadIdx.x >> 6);
    const int W = gridDim.x * 8;
    int grp = lane >> 3;     // 8 k's per wave-iteration
    int lp  = lane & 7;      // 16B (8 bf16 dims) per lane

    const int* kc = (const int*)ws + WS_KCODE;
    const unsigned short* bft = (const unsigned short*)((const char*)ws + WS_BF_BYTE);
    const int NGRP = 2 * KSEL / 8;   // 125000
    const int L2G  = KSEL / 8;       // 62500: layer-2 boundary (wave-uniform)

#define LDC(GI, CD, MK) { int gi_ = (GI); bool v_ = gi_ < NGRP; int kk_ = gi_ * 8 + grp; \
        CD = v_ ? kc[kk_] : N_NODES; \
        MK = (v_ && gi_ >= L2G) ? masks[kk_] : 0.f; }
#define LDR(CD, R) { int nd_ = (CD) & 0x1FFFF; \
        R = make_uint4(0u, 0u, 0u, 0u); \
        if (nd_ < N_NODES) R = *(const uint4*)(bft + (size_t)nd_ * 64 + lp * 8); }

    int cd0, cd1, cd2, cd3; float mk0, mk1, mk2, mk3;
    uint4 R0, R1, R2;
    LDC(wave,         cd0, mk0);
    LDC(wave + W,     cd1, mk1);
    LDC(wave + 2 * W, cd2, mk2);
    LDR(cd0, R0);
    LDR(cd1, R1);

    for (int gi = wave; gi < NGRP; gi += W) {
        LDR(cd2, R2);
        LDC(gi + 3 * W, cd3, mk3);

        int b = (cd0 >> 17) & 63;
        int g = (cd0 >> 23) & 63;
        float cu, cp;
        if (gi < L2G) {
            float w = sWd[g]; cu = w; cp = 1.f - w;
        } else {
            float lw = sWd[b]; float w1 = sWd[64 + g];
            cu = fmaf(mk0, w1, lw);
            cp = fmaf(mk0, 1.f - w1, 1.f - lw);
        }
        float4 tu0 = sU[b * 17 + 2 * lp], tu1 = sU[b * 17 + 2 * lp + 1];
        float4 tp0 = sP[b * 17 + 2 * lp], tp1 = sP[b * 17 + 2 * lp + 1];
        float f, val;
        f = uasf(R0.x << 16);         val  = (cu * tu0.x + cp * tp0.x) * f;
        f = uasf(R0.x & 0xFFFF0000u); val += (cu * tu0.y + cp * tp0.y) * f;
        f = uasf(R0.y << 16);         val += (cu * tu0.z + cp * tp0.z) * f;
        f = uasf(R0.y & 0xFFFF0000u); val += (cu * tu0.w + cp * tp0.w) * f;
        f = uasf(R0.z << 16);         val += (cu * tu1.x + cp * tp1.x) * f;
        f = uasf(R0.z & 0xFFFF0000u); val += (cu * tu1.y + cp * tp1.y) * f;
        f = uasf(R0.w << 16);         val += (cu * tu1.z + cp * tp1.z) * f;
        f = uasf(R0.w & 0xFFFF0000u); val += (cu * tu1.w + cp * tp1.w) * f;
        val += __shfl_xor(val, 1);
        val += __shfl_xor(val, 2);
        val += __shfl_xor(val, 4);
        if (lp == 0) out[gi * 8 + grp] = val;

        cd0 = cd1; mk0 = mk1; cd1 = cd2; mk1 = mk2; cd2 = cd3; mk2 = mk3;
        R0 = R1; R1 = R2;
    }
#undef LDC
#undef LDR
}

// ---------------------------------------------------------------------------
// Fallback kernels (ws too small for tables): round-7 proven versions.
// ---------------------------------------------------------------------------
#define KA2_L 25
__global__ __launch_bounds__(256) void kA2_fb(const float* __restrict__ ge,
                                              const int* __restrict__ mi,
                                              const int* __restrict__ mbi,
                                              float* __restrict__ ws) {
    int lane = threadIdx.x & 63;
    int wave = (blockIdx.x * 256 + threadIdx.x) >> 6;
    int wstart = wave * KA2_L;
    if (wstart >= NMENT) return;
    int wend = min(wstart + KA2_L, NMENT);
    int len  = wend - wstart;

    int idx    = wstart + lane;
    bool valid = idx < wend;
    int lastB  = mbi[wend - 1];
    int nd     = valid ? mi[idx] : 0;
    int bb     = valid ? mbi[idx] : lastB;
    float ebv  = valid ? ws[WS_EB + nd] : 0.f;
    int code   = nd | (bb << 17);

    float acc = 0.f, dacc = 0.f;
    int curb = __shfl(code, 0) >> 17;

    int Lr = (len + 3) & ~3;
    for (int u0 = 0; u0 < Lr; u0 += 4) {
        int c4[4]; float e4[4]; float x4[4];
#pragma unroll
        for (int j = 0; j < 4; ++j) {
            int u = u0 + j;
            c4[j] = __shfl(code, u);
            e4[j] = __shfl(ebv, u);
            x4[j] = ge[(size_t)(c4[j] & 0x1FFFF) * D_EMB + lane];
        }
#pragma unroll
        for (int j = 0; j < 4; ++j) {
            int b = c4[j] >> 17;
            if (b != curb) {
                atomicAdd(&ws[WS_NUM + curb * 64 + lane], acc);
                if (lane == 0) atomicAdd(&ws[WS_DEN + curb], dacc);
                acc = 0.f; dacc = 0.f; curb = b;
            }
            acc  = fmaf(e4[j], x4[j], acc);
            dacc += e4[j];
        }
    }
    atomicAdd(&ws[WS_NUM + curb * 64 + lane], acc);
    if (lane == 0) atomicAdd(&ws[WS_DEN + curb], dacc);
}

__global__ __launch_bounds__(512, 8) void kC_fb(const float* __restrict__ ge,
                                                const float* __restrict__ utter,
                                                const int* __restrict__ sel,
                                                const int* __restrict__ selb,
                                                const int* __restrict__ selg,
                                                const float* __restrict__ masks,
                                                const float* __restrict__ ws,
                                                float* __restrict__ out) {
    __shared__ float4 sU[64 * 17];
    __shared__ float4 sP[64 * 17];
    __shared__ float  sW[128];
    for (int i = threadIdx.x; i < 64 * 16; i += 512) {
        int r = i >> 4, c = i & 15;
        sU[r * 17 + c] = ((const float4*)utter)[i];
        sP[r * 17 + c] = ((const float4*)(ws + WS_PORT))[i];
    }
    if (threadIdx.x < 128) sW[threadIdx.x] = ws[WS_W + threadIdx.x];
    __syncthreads();

    int lane = threadIdx.x & 63;
    int wave = blockIdx.x * 8 + (threadIdx.x >> 6);
    int W = gridDim.x * 8;
    int grp = lane >> 4, lp = lane & 15;
    const float4* g4 = (const float4*)ge;
    const int NGRP = 2 * KSEL / 4;

    for (int gi = wave; gi < NGRP; gi += W) {
        int kk = gi * 4 + grp;
        int node = sel[kk], b = selb[kk], g = selg[kk];
        float cu, cp;
        if (kk < KSEL) { float w = sW[g]; cu = w; cp = 1.f - w; }
        else {
            float mask = masks[kk]; float lw = sW[b]; float w1 = sW[64 + g];
            cu = fmaf(mask, w1, lw); cp = fmaf(mask, 1.f - w1, 1.f - lw);
        }
        float4 f = make_float4(0.f, 0.f, 0.f, 0.f);
        if (node < N_NODES) f = g4[(size_t)node * 16 + lp];
        float4 tu = sU[b * 17 + lp];
        float4 tp = sP[b * 17 + lp];
        float val = (cu * tu.x + cp * tp.x) * f.x
                  + (cu * tu.y + cp * tp.y) * f.y
                  + (cu * tu.z + cp * tp.z) * f.z
                  + (cu * tu.w + cp * tp.w) * f.w;
        val += __shfl_xor(val, 1);
        val += __shfl_xor(val, 2);
        val += __shfl_xor(val, 4);
        val += __shfl_xor(val, 8);
        if (lp == 0) out[kk] = val;
    }
}

extern "C" void kernel_launch(void* const* d_in, const int* in_sizes, int n_in,
                              void* d_out, int out_size, void* d_ws, size_t ws_size,
                              hipStream_t stream) {
    const float* ge        = (const float*)d_in[0];
    const float* utter     = (const float*)d_in[1];
    const int*   mi        = (const int*)d_in[2];
    const int*   mbi       = (const int*)d_in[3];
    const int*   sel       = (const int*)d_in[4];
    const int*   selb      = (const int*)d_in[5];
    const int*   selg      = (const int*)d_in[6];
    const int*   grpb      = (const int*)d_in[7];
    const int*   lastI     = (const int*)d_in[8];
    const int*   intentI   = (const int*)d_in[9];
    const float* masks     = (const float*)d_in[10];
    const float* attW      = (const float*)d_in[11];
    const float* attV      = (const float*)d_in[12];
    const float* W1w       = (const float*)d_in[13];
    const float* W1b       = (const float*)d_in[14];
    const float* W2w       = (const float*)d_in[15];
    const float* W2b       = (const float*)d_in[16];
    const float* intentEmb = (const float*)d_in[17];
    float* ws  = (float*)d_ws;
    float* out = (float*)d_out;

    bool full = ws_size >= WS_TOTAL_BYTES;

    if (full) {
        kP<true><<<dim3(NPB + KCB), dim3(256), 0, stream>>>(
            ge, attW, attV, sel, selb, selg, ws);
        kA2n<<<dim3(2000), dim3(256), 0, stream>>>(mi, mbi, ws);
        kBW<<<dim3(128), dim3(64), 0, stream>>>(ge, utter, grpb, lastI, intentI,
                                                W1w, W1b, W2w, W2b, intentEmb, ws);
        kCn<<<dim3(1024), dim3(512), 0, stream>>>(utter, masks, ws, out);
    } else {
        kP<false><<<dim3(NPB), dim3(256), 0, stream>>>(
            ge, attW, attV, sel, selb, selg, ws);
        kA2_fb<<<dim3(2000), dim3(256), 0, stream>>>(ge, mi, mbi, ws);
        kBW<<<dim3(128), dim3(64), 0, stream>>>(ge, utter, grpb, lastI, intentI,
                                                W1w, W1b, W2w, W2b, intentEmb, ws);
        kC_fb<<<dim3(1024), dim3(512), 0, stream>>>(ge, utter, sel, selb, selg,
                                                    masks, ws, out);
    }
}